// Round 11
// baseline (339.691 us; speedup 1.0000x reference)
//
#include <hip/hip_runtime.h>
#include <cmath>

namespace {
constexpr float kE   = 3130.0f;
constexpr float kNu  = 0.37f;
constexpr float kSy0 = 64.8f;
constexpr float kH   = 100.0f;
constexpr float kG   = kE / (2.0f * (1.0f + kNu));
constexpr float kLam = kE * kNu / ((1.0f + kNu) * (1.0f - 2.0f * kNu));
constexpr float kC   = kE / ((1.0f + kNu) * (1.0f - 2.0f * kNu));
constexpr float kC11 = kC * (1.0f - kNu);
constexpr float kC12 = kC * kNu;
constexpr float kC2  = 3.0f * kG / (3.0f * kG + kH);  // 3G/(3G+H)
constexpr float kC3  = kH / (3.0f * kG + kH);         // 1 - kC2
constexpr int kS  = 2048;
constexpr int kT  = 16;
constexpr int kNBLK = kS / kT;   // 128
constexpr int kLs = 192;
constexpr float kSq15  = 1.224744871391589f;  // sqrt(1.5)
constexpr float kSq3   = 1.732050807568877f;  // sqrt(3)
constexpr float kISq15 = 1.0f / kSq15;
constexpr float kISq3  = 1.0f / kSq3;
}

typedef __fp16 half2_t __attribute__((ext_vector_type(2)));
typedef float f4_t __attribute__((ext_vector_type(4)));

__device__ __forceinline__ unsigned pk16(float a, float b) {
    half2_t h = __builtin_amdgcn_cvt_pkrtz(a, b);
    return __builtin_bit_cast(unsigned, h);
}
__device__ __forceinline__ float up16lo(unsigned u) {
    half2_t h = __builtin_bit_cast(half2_t, u);
    return (float)h.x;
}
__device__ __forceinline__ float up16hi(unsigned u) {
    half2_t h = __builtin_bit_cast(half2_t, u);
    return (float)h.y;
}

template<int CTRL, int RM, int BM>
__device__ __forceinline__ float dppmov(float v) {
    return __int_as_float(
        __builtin_amdgcn_update_dpp(0, __float_as_int(v), CTRL, RM, BM, false));
}
// wave64 sum, result in lane 63 (row_shr + row_bcast chain, VALU-only)
__device__ __forceinline__ float wave_sum63(float v) {
    v += dppmov<0x111, 0xf, 0xf>(v);
    v += dppmov<0x112, 0xf, 0xf>(v);
    v += dppmov<0x114, 0xf, 0xf>(v);
    v += dppmov<0x118, 0xf, 0xf>(v);
    v += dppmov<0x142, 0xa, 0xf>(v);
    v += dppmov<0x143, 0xc, 0xf>(v);
    return v;
}
// quad_perm DPP move (4-lane group reduce helper)
template<int CTRL>
__device__ __forceinline__ float qdpp(float v) {
    return __int_as_float(
        __builtin_amdgcn_update_dpp(0, __float_as_int(v), CTRL, 0xF, 0xF, true));
}

// pre-differenced strain-driver dx stream: (b, t) -> 3 floats
__device__ __align__(16) float g_dx[128 * 2048 * 3];   // 3.1 MB

// ===================== Kernel A: dx pre-difference ==========================
__global__ __launch_bounds__(256, 4)
void j2_dx(const float* __restrict__ x)
{
    const int gid = blockIdx.x * 256 + threadIdx.x;   // (b,t), 0..262143
    const int t = gid & 2047;
    const float* xe = x + (size_t)gid * 3;
    const float a0 = xe[0], a1 = xe[1], a2 = xe[2];
    float p0 = 0.f, p1 = 0.f, p2 = 0.f;
    if (t != 0) { p0 = xe[-3]; p1 = xe[-2]; p2 = xe[-1]; }
    float* o = g_dx + (size_t)gid * 3;
    o[0] = a0 - p0; o[1] = a1 - p1; o[2] = a2 - p2;
}

// =========== Kernel B: 4-chain-interleaved lane-parallel scan ===============
// Grid 128 (one WG = one wave = one batch). Lane = 4*kc + c; component c of
// chains {kc, 16+kc, 32+kc, 48+kc}. The 4 chains' recurrences are independent
// -> their ~130-cyc dependency chains overlap, wall/step -> max(issue, L/4).
// dx window is wave-uniform -> SGPR-resident (s_load); state fully unrolled
// in VGPRs. Store layout identical to R9 (einsum kernel unchanged).
__global__ __launch_bounds__(64, 1)
void j2_scan16(const float* __restrict__ W1, unsigned* __restrict__ ws32)
{
    const int b  = blockIdx.x;
    const int ln = threadIdx.x;
    const int kc = ln >> 2;             // quad index 0..15
    const int c  = ln & 3;              // component

    // per-chain component projection vectors
    float gv[4][3];
#pragma unroll
    for (int X = 0; X < 4; ++X) {
        const int kg = 16 * X + kc;
#pragma unroll
        for (int f = 0; f < 3; ++f) {
            const float w0 = W1[(3 * kg + 0) * 3 + f];
            const float w1 = W1[(3 * kg + 1) * 3 + f];
            const float w2 = W1[(3 * kg + 2) * 3 + f];
            const float e0 = kC11 * w0 + kC12 * w1;
            const float e1 = kC12 * w0 + kC11 * w1;
            const float lv = kLam * (w0 + w1);
            const float g0 = kSq15 * (2.0f * e0 - e1 - lv) * (1.0f / 3.0f);
            const float g1 = kSq15 * (2.0f * e1 - e0 - lv) * (1.0f / 3.0f);
            const float g2 = kSq3 * kG * w2;
            const float gz = -(g0 + g1);
            gv[X][f] = (c == 0) ? g0 : (c == 1) ? g1 : (c == 2) ? g2 : gz;
        }
    }

    const float* db = g_dx + (size_t)b * (kS * 3);
    unsigned* wsb = ws32 + (size_t)b * (1024 * 256) + ln;

    float s[4], y[4], c2y[4];
#pragma unroll
    for (int X = 0; X < 4; ++X) { s[X] = 0.f; y[X] = kSy0; c2y[X] = kC2 * kSy0; }

    auto loadw = [&](f4_t* dst, int p) {
        const f4_t* s4 = reinterpret_cast<const f4_t*>(db + p * 48);
#pragma unroll
        for (int i = 0; i < 12; ++i) dst[i] = s4[i];
    };

    auto body = [&](const f4_t* Wd, int p) {
        float se[4];
#pragma unroll
        for (int t = 0; t < kT; ++t) {
            const float d0 = Wd[(3 * t + 0) >> 2][(3 * t + 0) & 3];
            const float d1 = Wd[(3 * t + 1) >> 2][(3 * t + 1) & 3];
            const float d2 = Wd[(3 * t + 2) >> 2][(3 * t + 2) & 3];
#pragma unroll
            for (int X = 0; X < 4; ++X) {
                const float u  = fmaf(gv[X][0], d0,
                                 fmaf(gv[X][1], d1, gv[X][2] * d2));
                const float st = s[X] + u;
                float pp = fmaf(st, st, 2.5e-13f);    // 4 lanes -> 1e-12 total
                pp += qdpp<0xB1>(pp);                 // quad_perm [1,0,3,2]
                pp += qdpp<0x4E>(pp);                 // quad_perm [2,3,0,1]
                const float rq  = __builtin_amdgcn_rsqf(pp);
                const float fac = fminf(fmaf(c2y[X], rq, kC3), 1.0f);
                s[X] = fac * st;
                const float qv = pp * rq;
                y[X] = fmaxf(y[X], fmaf(kC3, qv, c2y[X]));
                c2y[X] = kC2 * y[X];
                if ((t & 1) == 0) se[X] = s[X];
            }
            if (t & 1) {
                const size_t o = (size_t)(p * 8 + (t >> 1)) * 256;
#pragma unroll
                for (int X = 0; X < 4; ++X)
                    wsb[o + X * 64] = pk16(se[X], s[X]);
            }
        }
    };

    f4_t A[12], B[12];
    loadw(A, 0);
    for (int p = 0; p < kNBLK; p += 2) {
        loadw(B, p + 1);
        body(A, p);
        if (p + 2 < kNBLK) loadw(A, p + 2);
        body(B, p + 1);
    }
}

// ========================= Kernel C: output einsum ==========================
// Lane k = chain k. uint4 per (b, t2, chain): x=pk(s0 even,odd) y=pk(s1)
// z=pk(s2) w=pk(sz, unused).
__global__ __launch_bounds__(64, 1)
void j2_out_einsum(const float* __restrict__ x,
                   const float* __restrict__ W1,
                   const float* __restrict__ W2,
                   const uint4* __restrict__ ws,
                   float* __restrict__ out)
{
    const int b = blockIdx.x;
    const int tile = blockIdx.y;
    const int k = threadIdx.x;

    float wr[3][3];
#pragma unroll
    for (int j = 0; j < 3; ++j)
#pragma unroll
        for (int f = 0; f < 3; ++f)
            wr[j][f] = W1[(3 * k + j) * 3 + f];
    float mv[3];
#pragma unroll
    for (int f = 0; f < 3; ++f) {
        const float e0 = kC11 * wr[0][f] + kC12 * wr[1][f];
        const float e1 = kC12 * wr[0][f] + kC11 * wr[1][f];
        const float lv = kLam * (wr[0][f] + wr[1][f]);
        mv[f] = (e0 + e1 + lv) * (1.0f / 3.0f);
    }
    float spp[3][3], so[3];
#pragma unroll
    for (int o = 0; o < 3; ++o) {
        const float a0 = __logf(1.0f + __expf(W2[o * kLs + 3 * k + 0]));
        const float a1 = __logf(1.0f + __expf(W2[o * kLs + 3 * k + 1]));
        const float a2 = __logf(1.0f + __expf(W2[o * kLs + 3 * k + 2]));
        spp[o][0] = a0 * kISq15;
        spp[o][1] = a1 * kISq15;
        spp[o][2] = a2 * kISq3;
        so[o] = a0 + a1;
    }

    float fx[48];
    {
        const float4* s4 = reinterpret_cast<const float4*>(
            x + (size_t)b * (kS * 3) + tile * 48);
#pragma unroll
        for (int i = 0; i < 12; ++i) {
            float4 v = s4[i];
            fx[4 * i]     = v.x; fx[4 * i + 1] = v.y;
            fx[4 * i + 2] = v.z; fx[4 * i + 3] = v.w;
        }
    }

    float r[48];
#pragma unroll
    for (int j = 0; j < 8; ++j) {
        const uint4 v = ws[((size_t)b * 1024 + tile * 8 + j) * 64 + k];
#pragma unroll
        for (int h = 0; h < 2; ++h) {
            const int t = 2 * j + h;
            const float sx = h ? up16hi(v.x) : up16lo(v.x);
            const float sy = h ? up16hi(v.y) : up16lo(v.y);
            const float sv = h ? up16hi(v.z) : up16lo(v.z);
            const float pm = fmaf(mv[0], fx[3 * t],
                             fmaf(mv[1], fx[3 * t + 1], mv[2] * fx[3 * t + 2]));
#pragma unroll
            for (int o = 0; o < 3; ++o) {
                const float A = fmaf(spp[o][0], sx,
                                fmaf(spp[o][1], sy, spp[o][2] * sv));
                r[3 * t + o] = fmaf(pm, so[o], A);
            }
        }
    }
#pragma unroll
    for (int v = 0; v < 48; ++v) r[v] = wave_sum63(r[v]);
    if (k == 63) {
        float4* o4 = reinterpret_cast<float4*>(
            out + (size_t)b * (kS * 3) + tile * 48);
#pragma unroll
        for (int i = 0; i < 12; ++i)
            o4[i] = make_float4(r[4 * i], r[4 * i + 1],
                                r[4 * i + 2], r[4 * i + 3]);
    }
}

// ================== Fallback: known-good R2 3-wave kernel ===================
__global__ __launch_bounds__(192, 1)
void j2_pc_kernel(const float* __restrict__ x,
                  const float* __restrict__ W1,
                  const float* __restrict__ W2,
                  float* __restrict__ out)
{
    __shared__ float4 ubuf[2][kT][64];
    __shared__ float4 sgbuf[2][kT][64];

    const int b = blockIdx.x;
    const int w = threadIdx.x >> 6;
    const int k = threadIdx.x & 63;

    const float* xb = x + (size_t)b * (kS * 3);
    float* ob = out + (size_t)b * (kS * 3);

    float e0[3], e1[3], e2[3], lv[3], sp[3][3];
    if (w != 0) {
        float wr[3][3];
#pragma unroll
        for (int j = 0; j < 3; ++j)
#pragma unroll
            for (int f = 0; f < 3; ++f)
                wr[j][f] = W1[(3 * k + j) * 3 + f];
#pragma unroll
        for (int f = 0; f < 3; ++f) {
            e0[f] = kC11 * wr[0][f] + kC12 * wr[1][f];
            e1[f] = kC12 * wr[0][f] + kC11 * wr[1][f];
            e2[f] = kG * wr[2][f];
            lv[f] = kLam * (wr[0][f] + wr[1][f]);
        }
#pragma unroll
        for (int o = 0; o < 3; ++o)
#pragma unroll
            for (int j = 0; j < 3; ++j) {
                float v = W2[o * kLs + 3 * k + j];
                sp[o][j] = log1pf(expf(v));
            }
    }

    float sg0 = 0.f, sg1 = 0.f, sg2 = 0.f, szz = 0.f;
    float y = kSy0;
    const int tlo = (w == 2) ? 8 : 0;
    constexpr float kInv3GH = 1.0f / (3.0f * kG + kH);
    constexpr float k3G = 3.0f * kG;

    for (int phase = 0; phase <= kNBLK + 1; ++phase) {
        if (w == 0) {
            if (phase >= 1 && phase <= kNBLK) {
                const int blk = phase - 1, pb = blk & 1;
                float4 u[kT];
#pragma unroll
                for (int t = 0; t < kT; ++t) u[t] = ubuf[pb][t][k];
#pragma unroll
                for (int t = 0; t < kT; ++t) {
                    const float t0 = sg0 + u[t].x;
                    const float t1 = sg1 + u[t].y;
                    const float t2 = sg2 + u[t].z;
                    const float tz = szz + u[t].w;
                    const float pm  = (t0 + t1 + tz) * (1.0f / 3.0f);
                    const float dxx = t0 - pm, dyy = t1 - pm, dzz = tz - pm;
                    const float sa  = fmaf(dxx, dxx, dyy * dyy);
                    const float sb  = fmaf(dzz, dzz, (2.0f * t2) * t2);
                    const float q2  = fmaf(1.5f, sa + sb, 1e-12f);
                    const float qq  = __builtin_amdgcn_sqrtf(q2);
                    const float rq  = __builtin_amdgcn_rcpf(qq);
                    const float f   = qq - y;
                    const float dg  = (f > 0.0f) ? f * kInv3GH : 0.0f;
                    y = fmaf(kH, dg, y);
                    const float fac = fmaf(-(k3G * dg), rq, 1.0f);
                    sg0 = fmaf(fac, dxx, pm);
                    sg1 = fmaf(fac, dyy, pm);
                    sg2 = fac * t2;
                    szz = fmaf(fac, dzz, pm);
                    sgbuf[pb][t][k] = make_float4(sg0, sg1, sg2, 0.f);
                }
            }
        } else {
            if (phase < kNBLK) {
                const int p = phase, pb = p & 1;
                float xv[28];
                if (w == 1) {
                    if (p == 0) {
                        xv[0] = xv[1] = xv[2] = xv[3] = 0.f;
                        const float4* s4 = reinterpret_cast<const float4*>(xb);
#pragma unroll
                        for (int i = 0; i < 6; ++i) {
                            float4 v = s4[i];
                            xv[4 + 4 * i] = v.x; xv[5 + 4 * i] = v.y;
                            xv[6 + 4 * i] = v.z; xv[7 + 4 * i] = v.w;
                        }
                    } else {
                        const float4* s4 =
                            reinterpret_cast<const float4*>(xb + p * 48 - 4);
#pragma unroll
                        for (int i = 0; i < 7; ++i) {
                            float4 v = s4[i];
                            xv[4 * i]     = v.x; xv[4 * i + 1] = v.y;
                            xv[4 * i + 2] = v.z; xv[4 * i + 3] = v.w;
                        }
                    }
                } else {
                    const float4* s4 =
                        reinterpret_cast<const float4*>(xb + p * 48 + 20);
#pragma unroll
                    for (int i = 0; i < 7; ++i) {
                        float4 v = s4[i];
                        xv[4 * i]     = v.x; xv[4 * i + 1] = v.y;
                        xv[4 * i + 2] = v.z; xv[4 * i + 3] = v.w;
                    }
                }
                const int tbase = (w == 2) ? 8 : 0;
#pragma unroll
                for (int t = 0; t < 8; ++t) {
                    const float dx0 = xv[3 * t + 4] - xv[3 * t + 1];
                    const float dx1 = xv[3 * t + 5] - xv[3 * t + 2];
                    const float dx2 = xv[3 * t + 6] - xv[3 * t + 3];
                    float4 u;
                    u.x = fmaf(e0[0], dx0, fmaf(e0[1], dx1, e0[2] * dx2));
                    u.y = fmaf(e1[0], dx0, fmaf(e1[1], dx1, e1[2] * dx2));
                    u.z = fmaf(e2[0], dx0, fmaf(e2[1], dx1, e2[2] * dx2));
                    u.w = fmaf(lv[0], dx0, fmaf(lv[1], dx1, lv[2] * dx2));
                    ubuf[pb][tbase + t][k] = u;
                }
            }
            if (phase >= 2) {
                const int q = phase - 2, qb = q & 1;
                const int tbase = tlo;
                float r[24];
#pragma unroll
                for (int t = 0; t < 8; ++t) {
                    float4 s = sgbuf[qb][tbase + t][k];
                    r[3 * t]     = fmaf(sp[0][0], s.x, fmaf(sp[0][1], s.y, sp[0][2] * s.z));
                    r[3 * t + 1] = fmaf(sp[1][0], s.x, fmaf(sp[1][1], s.y, sp[1][2] * s.z));
                    r[3 * t + 2] = fmaf(sp[2][0], s.x, fmaf(sp[2][1], s.y, sp[2][2] * s.z));
                }
#pragma unroll
                for (int v = 0; v < 24; ++v) r[v] = wave_sum63(r[v]);
                if (k == 63) {
                    float4* o4 = reinterpret_cast<float4*>(ob + q * 48 + tbase * 3);
#pragma unroll
                    for (int i = 0; i < 6; ++i)
                        o4[i] = make_float4(r[4 * i], r[4 * i + 1],
                                            r[4 * i + 2], r[4 * i + 3]);
                }
            }
        }
        __syncthreads();
    }
}

extern "C" void kernel_launch(void* const* d_in, const int* in_sizes, int n_in,
                              void* d_out, int out_size, void* d_ws, size_t ws_size,
                              hipStream_t stream) {
    const float* x  = (const float*)d_in[0];   // (128, 2048, 3)
    const float* W1 = (const float*)d_in[1];   // (192, 3)
    const float* W2 = (const float*)d_in[2];   // (3, 192)
    float* out = (float*)d_out;                // (128, 2048, 3)

    const size_t need = (size_t)128 * 1024 * 64 * sizeof(uint4);  // 128 MiB
    if (ws_size >= need) {
        j2_dx<<<dim3(1024), dim3(256), 0, stream>>>(x);
        j2_scan16<<<dim3(128), dim3(64), 0, stream>>>(W1, (unsigned*)d_ws);
        j2_out_einsum<<<dim3(128, 128), dim3(64), 0, stream>>>(
            x, W1, W2, (const uint4*)d_ws, out);
    } else {
        j2_pc_kernel<<<dim3(128), dim3(192), 0, stream>>>(x, W1, W2, out);
    }
}

// Round 12
// 202.977 us; speedup vs baseline: 1.6735x; 1.6735x over previous
//
#include <hip/hip_runtime.h>
#include <cmath>

namespace {
constexpr float kE   = 3130.0f;
constexpr float kNu  = 0.37f;
constexpr float kSy0 = 64.8f;
constexpr float kH   = 100.0f;
constexpr float kG   = kE / (2.0f * (1.0f + kNu));
constexpr float kLam = kE * kNu / ((1.0f + kNu) * (1.0f - 2.0f * kNu));
constexpr float kC   = kE / ((1.0f + kNu) * (1.0f - 2.0f * kNu));
constexpr float kC11 = kC * (1.0f - kNu);
constexpr float kC12 = kC * kNu;
constexpr float kC2  = 3.0f * kG / (3.0f * kG + kH);  // 3G/(3G+H)
constexpr float kC3  = kH / (3.0f * kG + kH);         // 1 - kC2
constexpr int kS  = 2048;
constexpr int kT  = 16;
constexpr int kNBLK = kS / kT;   // 128
constexpr int kLs = 192;
constexpr float kSq15  = 1.224744871391589f;  // sqrt(1.5)
constexpr float kSq3   = 1.732050807568877f;  // sqrt(3)
constexpr float kISq15 = 1.0f / kSq15;
constexpr float kISq3  = 1.0f / kSq3;
}

typedef __fp16 half2_t __attribute__((ext_vector_type(2)));
typedef float f4_t __attribute__((ext_vector_type(4)));

__device__ __forceinline__ unsigned pk16(float a, float b) {
    half2_t h = __builtin_amdgcn_cvt_pkrtz(a, b);
    return __builtin_bit_cast(unsigned, h);
}
__device__ __forceinline__ float up16lo(unsigned u) {
    half2_t h = __builtin_bit_cast(half2_t, u);
    return (float)h.x;
}
__device__ __forceinline__ float up16hi(unsigned u) {
    half2_t h = __builtin_bit_cast(half2_t, u);
    return (float)h.y;
}

template<int CTRL, int RM, int BM>
__device__ __forceinline__ float dppmov(float v) {
    return __int_as_float(
        __builtin_amdgcn_update_dpp(0, __float_as_int(v), CTRL, RM, BM, false));
}
// wave64 sum, result in lane 63 (row_shr + row_bcast chain, VALU-only)
__device__ __forceinline__ float wave_sum63(float v) {
    v += dppmov<0x111, 0xf, 0xf>(v);
    v += dppmov<0x112, 0xf, 0xf>(v);
    v += dppmov<0x114, 0xf, 0xf>(v);
    v += dppmov<0x118, 0xf, 0xf>(v);
    v += dppmov<0x142, 0xa, 0xf>(v);
    v += dppmov<0x143, 0xc, 0xf>(v);
    return v;
}
// quad_perm DPP move (4-lane group reduce helper)
template<int CTRL>
__device__ __forceinline__ float qdpp(float v) {
    return __int_as_float(
        __builtin_amdgcn_update_dpp(0, __float_as_int(v), CTRL, 0xF, 0xF, true));
}

// pre-differenced strain-driver dx stream: (b, t) -> 3 floats
__device__ __align__(16) float g_dx[128 * 2048 * 3];   // 3.1 MB

// ===================== Kernel A: dx pre-difference ==========================
__global__ __launch_bounds__(256, 4)
void j2_dx(const float* __restrict__ x)
{
    const int gid = blockIdx.x * 256 + threadIdx.x;   // (b,t), 0..262143
    const int t = gid & 2047;
    const float* xe = x + (size_t)gid * 3;
    const float a0 = xe[0], a1 = xe[1], a2 = xe[2];
    float p0 = 0.f, p1 = 0.f, p2 = 0.f;
    if (t != 0) { p0 = xe[-3]; p1 = xe[-2]; p2 = xe[-1]; }
    float* o = g_dx + (size_t)gid * 3;
    o[0] = a0 - p0; o[1] = a1 - p1; o[2] = a2 - p2;
}

// ====== Kernel B: lane-parallel component scan, 2-waves-per-SIMD pack ======
// 64 WGs x 512 threads (8 waves). Wave w handles (batch, quarter) =
// ((bid*8+w)>>2, (bid*8+w)&3) — identical per-wave code to R9's j2_scan4,
// but 8 waves/WG -> 2 waves per SIMD co-resident: each wave's ~63-cyc
// recurrence stall is filled by the other wave's issue stream (TLP).
// No barriers, no LDS; waves fully independent.
__global__ __launch_bounds__(512, 1)
void j2_scan4p(const float* __restrict__ W1, unsigned* __restrict__ ws32)
{
    const int wslot = blockIdx.x * 8 + (threadIdx.x >> 6);  // 0..511
    const int b   = wslot >> 2;
    const int qtr = wslot & 3;
    const int ln  = threadIdx.x & 63;
    const int kc  = ln >> 2;            // local chain 0..15
    const int c   = ln & 3;             // component
    const int kg  = qtr * 16 + kc;      // chain within batch 0..63

    // own component's projection vector g[3]
    float gv[3];
#pragma unroll
    for (int f = 0; f < 3; ++f) {
        const float w0 = W1[(3 * kg + 0) * 3 + f];
        const float w1 = W1[(3 * kg + 1) * 3 + f];
        const float w2 = W1[(3 * kg + 2) * 3 + f];
        const float e0 = kC11 * w0 + kC12 * w1;
        const float e1 = kC12 * w0 + kC11 * w1;
        const float lv = kLam * (w0 + w1);
        const float g0 = kSq15 * (2.0f * e0 - e1 - lv) * (1.0f / 3.0f);
        const float g1 = kSq15 * (2.0f * e1 - e0 - lv) * (1.0f / 3.0f);
        const float g2 = kSq3 * kG * w2;
        const float gz = -(g0 + g1);
        gv[f] = (c == 0) ? g0 : (c == 1) ? g1 : (c == 2) ? g2 : gz;
    }

    const float* db = g_dx + (size_t)b * (kS * 3);
    unsigned* wsb = ws32 + (size_t)b * 1024 * 256 + qtr * 64 + ln;

    float s = 0.f, y = kSy0, c2y = kC2 * kSy0;

    auto loadw = [&](f4_t* dst, int p) {
        const f4_t* s4 = reinterpret_cast<const f4_t*>(db + p * 48);
#pragma unroll
        for (int i = 0; i < 12; ++i) dst[i] = s4[i];
    };

    auto body = [&](const f4_t* Wd, int p) {
        float u[kT];
#pragma unroll
        for (int t = 0; t < kT; ++t) {
            const float d0 = Wd[(3 * t + 0) >> 2][(3 * t + 0) & 3];
            const float d1 = Wd[(3 * t + 1) >> 2][(3 * t + 1) & 3];
            const float d2 = Wd[(3 * t + 2) >> 2][(3 * t + 2) & 3];
            u[t] = fmaf(gv[0], d0, fmaf(gv[1], d1, gv[2] * d2));
        }
        float se = 0.f;
#pragma unroll
        for (int t = 0; t < kT; ++t) {
            const float st = s + u[t];
            float pp = fmaf(st, st, 2.5e-13f);      // 4 lanes -> +1e-12 total
            pp += qdpp<0xB1>(pp);                   // quad_perm [1,0,3,2]
            pp += qdpp<0x4E>(pp);                   // quad_perm [2,3,0,1]
            const float rq  = __builtin_amdgcn_rsqf(pp);
            const float fac = fminf(fmaf(c2y, rq, kC3), 1.0f);
            s = fac * st;
            const float qv = pp * rq;
            y = fmaxf(y, fmaf(kC3, qv, c2y));
            c2y = kC2 * y;
            if ((t & 1) == 0) {
                se = s;
            } else {
                wsb[(size_t)(p * 8 + (t >> 1)) * 256] = pk16(se, s);
            }
        }
    };

    f4_t A[12], B[12];
    loadw(A, 0);
    for (int p = 0; p < kNBLK; p += 2) {
        loadw(B, p + 1);
        body(A, p);
        if (p + 2 < kNBLK) loadw(A, p + 2);
        body(B, p + 1);
    }
}

// ========================= Kernel C: output einsum ==========================
// Lane k = chain k. uint4 per (b, t2, chain): x=pk(s0 even,odd) y=pk(s1)
// z=pk(s2) w=pk(sz, unused).
__global__ __launch_bounds__(64, 1)
void j2_out_einsum(const float* __restrict__ x,
                   const float* __restrict__ W1,
                   const float* __restrict__ W2,
                   const uint4* __restrict__ ws,
                   float* __restrict__ out)
{
    const int b = blockIdx.x;
    const int tile = blockIdx.y;
    const int k = threadIdx.x;

    float wr[3][3];
#pragma unroll
    for (int j = 0; j < 3; ++j)
#pragma unroll
        for (int f = 0; f < 3; ++f)
            wr[j][f] = W1[(3 * k + j) * 3 + f];
    float mv[3];
#pragma unroll
    for (int f = 0; f < 3; ++f) {
        const float e0 = kC11 * wr[0][f] + kC12 * wr[1][f];
        const float e1 = kC12 * wr[0][f] + kC11 * wr[1][f];
        const float lv = kLam * (wr[0][f] + wr[1][f]);
        mv[f] = (e0 + e1 + lv) * (1.0f / 3.0f);
    }
    float spp[3][3], so[3];
#pragma unroll
    for (int o = 0; o < 3; ++o) {
        const float a0 = __logf(1.0f + __expf(W2[o * kLs + 3 * k + 0]));
        const float a1 = __logf(1.0f + __expf(W2[o * kLs + 3 * k + 1]));
        const float a2 = __logf(1.0f + __expf(W2[o * kLs + 3 * k + 2]));
        spp[o][0] = a0 * kISq15;
        spp[o][1] = a1 * kISq15;
        spp[o][2] = a2 * kISq3;
        so[o] = a0 + a1;
    }

    float fx[48];
    {
        const float4* s4 = reinterpret_cast<const float4*>(
            x + (size_t)b * (kS * 3) + tile * 48);
#pragma unroll
        for (int i = 0; i < 12; ++i) {
            float4 v = s4[i];
            fx[4 * i]     = v.x; fx[4 * i + 1] = v.y;
            fx[4 * i + 2] = v.z; fx[4 * i + 3] = v.w;
        }
    }

    float r[48];
#pragma unroll
    for (int j = 0; j < 8; ++j) {
        const uint4 v = ws[((size_t)b * 1024 + tile * 8 + j) * 64 + k];
#pragma unroll
        for (int h = 0; h < 2; ++h) {
            const int t = 2 * j + h;
            const float sx = h ? up16hi(v.x) : up16lo(v.x);
            const float sy = h ? up16hi(v.y) : up16lo(v.y);
            const float sv = h ? up16hi(v.z) : up16lo(v.z);
            const float pm = fmaf(mv[0], fx[3 * t],
                             fmaf(mv[1], fx[3 * t + 1], mv[2] * fx[3 * t + 2]));
#pragma unroll
            for (int o = 0; o < 3; ++o) {
                const float A = fmaf(spp[o][0], sx,
                                fmaf(spp[o][1], sy, spp[o][2] * sv));
                r[3 * t + o] = fmaf(pm, so[o], A);
            }
        }
    }
#pragma unroll
    for (int v = 0; v < 48; ++v) r[v] = wave_sum63(v == 0 ? r[0] : r[v]);
    if (k == 63) {
        float4* o4 = reinterpret_cast<float4*>(
            out + (size_t)b * (kS * 3) + tile * 48);
#pragma unroll
        for (int i = 0; i < 12; ++i)
            o4[i] = make_float4(r[4 * i], r[4 * i + 1],
                                r[4 * i + 2], r[4 * i + 3]);
    }
}

// ================== Fallback: known-good R2 3-wave kernel ===================
__global__ __launch_bounds__(192, 1)
void j2_pc_kernel(const float* __restrict__ x,
                  const float* __restrict__ W1,
                  const float* __restrict__ W2,
                  float* __restrict__ out)
{
    __shared__ float4 ubuf[2][kT][64];
    __shared__ float4 sgbuf[2][kT][64];

    const int b = blockIdx.x;
    const int w = threadIdx.x >> 6;
    const int k = threadIdx.x & 63;

    const float* xb = x + (size_t)b * (kS * 3);
    float* ob = out + (size_t)b * (kS * 3);

    float e0[3], e1[3], e2[3], lv[3], sp[3][3];
    if (w != 0) {
        float wr[3][3];
#pragma unroll
        for (int j = 0; j < 3; ++j)
#pragma unroll
            for (int f = 0; f < 3; ++f)
                wr[j][f] = W1[(3 * k + j) * 3 + f];
#pragma unroll
        for (int f = 0; f < 3; ++f) {
            e0[f] = kC11 * wr[0][f] + kC12 * wr[1][f];
            e1[f] = kC12 * wr[0][f] + kC11 * wr[1][f];
            e2[f] = kG * wr[2][f];
            lv[f] = kLam * (wr[0][f] + wr[1][f]);
        }
#pragma unroll
        for (int o = 0; o < 3; ++o)
#pragma unroll
            for (int j = 0; j < 3; ++j) {
                float v = W2[o * kLs + 3 * k + j];
                sp[o][j] = log1pf(expf(v));
            }
    }

    float sg0 = 0.f, sg1 = 0.f, sg2 = 0.f, szz = 0.f;
    float y = kSy0;
    const int tlo = (w == 2) ? 8 : 0;
    constexpr float kInv3GH = 1.0f / (3.0f * kG + kH);
    constexpr float k3G = 3.0f * kG;

    for (int phase = 0; phase <= kNBLK + 1; ++phase) {
        if (w == 0) {
            if (phase >= 1 && phase <= kNBLK) {
                const int blk = phase - 1, pb = blk & 1;
                float4 u[kT];
#pragma unroll
                for (int t = 0; t < kT; ++t) u[t] = ubuf[pb][t][k];
#pragma unroll
                for (int t = 0; t < kT; ++t) {
                    const float t0 = sg0 + u[t].x;
                    const float t1 = sg1 + u[t].y;
                    const float t2 = sg2 + u[t].z;
                    const float tz = szz + u[t].w;
                    const float pm  = (t0 + t1 + tz) * (1.0f / 3.0f);
                    const float dxx = t0 - pm, dyy = t1 - pm, dzz = tz - pm;
                    const float sa  = fmaf(dxx, dxx, dyy * dyy);
                    const float sb  = fmaf(dzz, dzz, (2.0f * t2) * t2);
                    const float q2  = fmaf(1.5f, sa + sb, 1e-12f);
                    const float qq  = __builtin_amdgcn_sqrtf(q2);
                    const float rq  = __builtin_amdgcn_rcpf(qq);
                    const float f   = qq - y;
                    const float dg  = (f > 0.0f) ? f * kInv3GH : 0.0f;
                    y = fmaf(kH, dg, y);
                    const float fac = fmaf(-(k3G * dg), rq, 1.0f);
                    sg0 = fmaf(fac, dxx, pm);
                    sg1 = fmaf(fac, dyy, pm);
                    sg2 = fac * t2;
                    szz = fmaf(fac, dzz, pm);
                    sgbuf[pb][t][k] = make_float4(sg0, sg1, sg2, 0.f);
                }
            }
        } else {
            if (phase < kNBLK) {
                const int p = phase, pb = p & 1;
                float xv[28];
                if (w == 1) {
                    if (p == 0) {
                        xv[0] = xv[1] = xv[2] = xv[3] = 0.f;
                        const float4* s4 = reinterpret_cast<const float4*>(xb);
#pragma unroll
                        for (int i = 0; i < 6; ++i) {
                            float4 v = s4[i];
                            xv[4 + 4 * i] = v.x; xv[5 + 4 * i] = v.y;
                            xv[6 + 4 * i] = v.z; xv[7 + 4 * i] = v.w;
                        }
                    } else {
                        const float4* s4 =
                            reinterpret_cast<const float4*>(xb + p * 48 - 4);
#pragma unroll
                        for (int i = 0; i < 7; ++i) {
                            float4 v = s4[i];
                            xv[4 * i]     = v.x; xv[4 * i + 1] = v.y;
                            xv[4 * i + 2] = v.z; xv[4 * i + 3] = v.w;
                        }
                    }
                } else {
                    const float4* s4 =
                        reinterpret_cast<const float4*>(xb + p * 48 + 20);
#pragma unroll
                    for (int i = 0; i < 7; ++i) {
                        float4 v = s4[i];
                        xv[4 * i]     = v.x; xv[4 * i + 1] = v.y;
                        xv[4 * i + 2] = v.z; xv[4 * i + 3] = v.w;
                    }
                }
                const int tbase = (w == 2) ? 8 : 0;
#pragma unroll
                for (int t = 0; t < 8; ++t) {
                    const float dx0 = xv[3 * t + 4] - xv[3 * t + 1];
                    const float dx1 = xv[3 * t + 5] - xv[3 * t + 2];
                    const float dx2 = xv[3 * t + 6] - xv[3 * t + 3];
                    float4 u;
                    u.x = fmaf(e0[0], dx0, fmaf(e0[1], dx1, e0[2] * dx2));
                    u.y = fmaf(e1[0], dx0, fmaf(e1[1], dx1, e1[2] * dx2));
                    u.z = fmaf(e2[0], dx0, fmaf(e2[1], dx1, e2[2] * dx2));
                    u.w = fmaf(lv[0], dx0, fmaf(lv[1], dx1, lv[2] * dx2));
                    ubuf[pb][tbase + t][k] = u;
                }
            }
            if (phase >= 2) {
                const int q = phase - 2, qb = q & 1;
                const int tbase = tlo;
                float r[24];
#pragma unroll
                for (int t = 0; t < 8; ++t) {
                    float4 s = sgbuf[qb][tbase + t][k];
                    r[3 * t]     = fmaf(sp[0][0], s.x, fmaf(sp[0][1], s.y, sp[0][2] * s.z));
                    r[3 * t + 1] = fmaf(sp[1][0], s.x, fmaf(sp[1][1], s.y, sp[1][2] * s.z));
                    r[3 * t + 2] = fmaf(sp[2][0], s.x, fmaf(sp[2][1], s.y, sp[2][2] * s.z));
                }
#pragma unroll
                for (int v = 0; v < 24; ++v) r[v] = wave_sum63(r[v]);
                if (k == 63) {
                    float4* o4 = reinterpret_cast<float4*>(ob + q * 48 + tbase * 3);
#pragma unroll
                    for (int i = 0; i < 6; ++i)
                        o4[i] = make_float4(r[4 * i], r[4 * i + 1],
                                            r[4 * i + 2], r[4 * i + 3]);
                }
            }
        }
        __syncthreads();
    }
}

extern "C" void kernel_launch(void* const* d_in, const int* in_sizes, int n_in,
                              void* d_out, int out_size, void* d_ws, size_t ws_size,
                              hipStream_t stream) {
    const float* x  = (const float*)d_in[0];   // (128, 2048, 3)
    const float* W1 = (const float*)d_in[1];   // (192, 3)
    const float* W2 = (const float*)d_in[2];   // (3, 192)
    float* out = (float*)d_out;                // (128, 2048, 3)

    const size_t need = (size_t)128 * 1024 * 64 * sizeof(uint4);  // 128 MiB
    if (ws_size >= need) {
        j2_dx<<<dim3(1024), dim3(256), 0, stream>>>(x);
        j2_scan4p<<<dim3(64), dim3(512), 0, stream>>>(W1, (unsigned*)d_ws);
        j2_out_einsum<<<dim3(128, 128), dim3(64), 0, stream>>>(
            x, W1, W2, (const uint4*)d_ws, out);
    } else {
        j2_pc_kernel<<<dim3(128), dim3(192), 0, stream>>>(x, W1, W2, out);
    }
}

// Round 13
// 168.446 us; speedup vs baseline: 2.0166x; 1.2050x over previous
//
#include <hip/hip_runtime.h>
#include <cmath>

namespace {
constexpr float kE   = 3130.0f;
constexpr float kNu  = 0.37f;
constexpr float kSy0 = 64.8f;
constexpr float kH   = 100.0f;
constexpr float kG   = kE / (2.0f * (1.0f + kNu));
constexpr float kLam = kE * kNu / ((1.0f + kNu) * (1.0f - 2.0f * kNu));
constexpr float kC   = kE / ((1.0f + kNu) * (1.0f - 2.0f * kNu));
constexpr float kC11 = kC * (1.0f - kNu);
constexpr float kC12 = kC * kNu;
constexpr float kC2  = 3.0f * kG / (3.0f * kG + kH);  // 3G/(3G+H)
constexpr float kC3  = kH / (3.0f * kG + kH);         // 1 - kC2
constexpr int kS  = 2048;
constexpr int kT  = 16;
constexpr int kNBLK = kS / kT;   // 128
constexpr int kLs = 192;
constexpr float kSq15  = 1.224744871391589f;  // sqrt(1.5)
constexpr float kSq3   = 1.732050807568877f;  // sqrt(3)
constexpr float kISq15 = 1.0f / kSq15;
constexpr float kISq3  = 1.0f / kSq3;
}

typedef __fp16 half2_t __attribute__((ext_vector_type(2)));
typedef float f4_t __attribute__((ext_vector_type(4)));

__device__ __forceinline__ unsigned pk16(float a, float b) {
    half2_t h = __builtin_amdgcn_cvt_pkrtz(a, b);
    return __builtin_bit_cast(unsigned, h);
}
__device__ __forceinline__ float up16lo(unsigned u) {
    half2_t h = __builtin_bit_cast(half2_t, u);
    return (float)h.x;
}
__device__ __forceinline__ float up16hi(unsigned u) {
    half2_t h = __builtin_bit_cast(half2_t, u);
    return (float)h.y;
}

template<int CTRL, int RM, int BM>
__device__ __forceinline__ float dppmov(float v) {
    return __int_as_float(
        __builtin_amdgcn_update_dpp(0, __float_as_int(v), CTRL, RM, BM, false));
}
// wave64 sum, result in lane 63 (row_shr + row_bcast chain, VALU-only)
__device__ __forceinline__ float wave_sum63(float v) {
    v += dppmov<0x111, 0xf, 0xf>(v);
    v += dppmov<0x112, 0xf, 0xf>(v);
    v += dppmov<0x114, 0xf, 0xf>(v);
    v += dppmov<0x118, 0xf, 0xf>(v);
    v += dppmov<0x142, 0xa, 0xf>(v);
    v += dppmov<0x143, 0xc, 0xf>(v);
    return v;
}
// quad_perm DPP move (bound_ctrl=1)
template<int CTRL>
__device__ __forceinline__ float qdpp(float v) {
    return __int_as_float(
        __builtin_amdgcn_update_dpp(0, __float_as_int(v), CTRL, 0xF, 0xF, true));
}

// pre-differenced strain-driver dx stream: (b, t) -> 3 floats
__device__ __align__(16) float g_dx[128 * 2048 * 3];   // 3.1 MB

// ===================== Kernel A: dx pre-difference ==========================
__global__ __launch_bounds__(256, 4)
void j2_dx(const float* __restrict__ x)
{
    const int gid = blockIdx.x * 256 + threadIdx.x;   // (b,t), 0..262143
    const int t = gid & 2047;
    const float* xe = x + (size_t)gid * 3;
    const float a0 = xe[0], a1 = xe[1], a2 = xe[2];
    float p0 = 0.f, p1 = 0.f, p2 = 0.f;
    if (t != 0) { p0 = xe[-3]; p1 = xe[-2]; p2 = xe[-1]; }
    float* o = g_dx + (size_t)gid * 3;
    o[0] = a0 - p0; o[1] = a1 - p1; o[2] = a2 - p2;
}

// ============ Kernel B: 2-lanes-per-chain component-paired scan =============
// 256 WGs x 1 wave (WG = (batch, half)). Lane = 2*kc + c2:
//   c2=0 owns (s0h, s1h); c2=1 owns (s2h, szh).
// q2 = own two squares + ONE pair-swap DPP add (vs 2 DPP levels at 4-lane).
// Per-lane ~21 inst/step (vs 4-lane's ~16.5 but half the lanes per chain
// and one less DPP hop on the serial chain). ws layout identical to R9.
__global__ __launch_bounds__(64, 1)
void j2_scan2l(const float* __restrict__ W1, uint2* __restrict__ ws2)
{
    const int b    = blockIdx.x >> 1;
    const int half = blockIdx.x & 1;
    const int ln   = threadIdx.x;
    const int kc   = ln >> 1;            // local chain 0..31
    const int c2   = ln & 1;             // component pair selector
    const int kg   = half * 32 + kc;     // chain within batch 0..63

    // this lane's two projection vectors
    float ga[3], gb[3];
#pragma unroll
    for (int f = 0; f < 3; ++f) {
        const float w0 = W1[(3 * kg + 0) * 3 + f];
        const float w1 = W1[(3 * kg + 1) * 3 + f];
        const float w2 = W1[(3 * kg + 2) * 3 + f];
        const float e0 = kC11 * w0 + kC12 * w1;
        const float e1 = kC12 * w0 + kC11 * w1;
        const float lv = kLam * (w0 + w1);
        const float g0 = kSq15 * (2.0f * e0 - e1 - lv) * (1.0f / 3.0f);
        const float g1 = kSq15 * (2.0f * e1 - e0 - lv) * (1.0f / 3.0f);
        const float g2 = kSq3 * kG * w2;
        const float gz = -(g0 + g1);
        ga[f] = c2 ? g2 : g0;
        gb[f] = c2 ? gz : g1;
    }
    const float eps = c2 ? 0.0f : 1e-12f;

    const float* db = g_dx + (size_t)b * (kS * 3);
    // uint2 index: ((p*8 + j)*64 + kg)*2 + c2, plus batch base b*1024*64*2
    uint2* wsb = ws2 + (size_t)b * (1024 * 128) + kg * 2 + c2;

    float sA = 0.f, sB = 0.f, y = kSy0, c2y = kC2 * kSy0;

    auto loadw = [&](f4_t* dst, int p) {
        const f4_t* s4 = reinterpret_cast<const f4_t*>(db + p * 48);
#pragma unroll
        for (int i = 0; i < 12; ++i) dst[i] = s4[i];
    };

    auto body = [&](const f4_t* Wd, int p) {
        float seA = 0.f, seB = 0.f;
#pragma unroll
        for (int t = 0; t < kT; ++t) {
            const float d0 = Wd[(3 * t + 0) >> 2][(3 * t + 0) & 3];
            const float d1 = Wd[(3 * t + 1) >> 2][(3 * t + 1) & 3];
            const float d2 = Wd[(3 * t + 2) >> 2][(3 * t + 2) & 3];
            const float uA = fmaf(ga[0], d0, fmaf(ga[1], d1, ga[2] * d2));
            const float uB = fmaf(gb[0], d0, fmaf(gb[1], d1, gb[2] * d2));
            const float stA = sA + uA;
            const float stB = sB + uB;
            float pp = fmaf(stA, stA, eps);
            pp = fmaf(stB, stB, pp);
            pp += qdpp<0xB1>(pp);               // pair swap: q2 on both lanes
            const float rq  = __builtin_amdgcn_rsqf(pp);
            const float fac = fminf(fmaf(c2y, rq, kC3), 1.0f);
            sA = fac * stA;
            sB = fac * stB;
            const float qv = pp * rq;
            y = fmaxf(y, fmaf(kC3, qv, c2y));
            c2y = kC2 * y;
            if ((t & 1) == 0) {
                seA = sA; seB = sB;
            } else {
                wsb[(size_t)(p * 8 + (t >> 1)) * 128] =
                    make_uint2(pk16(seA, sA), pk16(seB, sB));
            }
        }
    };

    f4_t A[12], B[12];
    loadw(A, 0);
    for (int p = 0; p < kNBLK; p += 2) {
        loadw(B, p + 1);
        body(A, p);
        if (p + 2 < kNBLK) loadw(A, p + 2);
        body(B, p + 1);
    }
}

// ========================= Kernel C: output einsum ==========================
// Lane k = chain k. uint4 per (b, t2, chain): x=pk(s0 even,odd) y=pk(s1)
// z=pk(s2) w=pk(sz, unused).
__global__ __launch_bounds__(64, 1)
void j2_out_einsum(const float* __restrict__ x,
                   const float* __restrict__ W1,
                   const float* __restrict__ W2,
                   const uint4* __restrict__ ws,
                   float* __restrict__ out)
{
    const int b = blockIdx.x;
    const int tile = blockIdx.y;
    const int k = threadIdx.x;

    float wr[3][3];
#pragma unroll
    for (int j = 0; j < 3; ++j)
#pragma unroll
        for (int f = 0; f < 3; ++f)
            wr[j][f] = W1[(3 * k + j) * 3 + f];
    float mv[3];
#pragma unroll
    for (int f = 0; f < 3; ++f) {
        const float e0 = kC11 * wr[0][f] + kC12 * wr[1][f];
        const float e1 = kC12 * wr[0][f] + kC11 * wr[1][f];
        const float lv = kLam * (wr[0][f] + wr[1][f]);
        mv[f] = (e0 + e1 + lv) * (1.0f / 3.0f);
    }
    float spp[3][3], so[3];
#pragma unroll
    for (int o = 0; o < 3; ++o) {
        const float a0 = __logf(1.0f + __expf(W2[o * kLs + 3 * k + 0]));
        const float a1 = __logf(1.0f + __expf(W2[o * kLs + 3 * k + 1]));
        const float a2 = __logf(1.0f + __expf(W2[o * kLs + 3 * k + 2]));
        spp[o][0] = a0 * kISq15;
        spp[o][1] = a1 * kISq15;
        spp[o][2] = a2 * kISq3;
        so[o] = a0 + a1;
    }

    float fx[48];
    {
        const float4* s4 = reinterpret_cast<const float4*>(
            x + (size_t)b * (kS * 3) + tile * 48);
#pragma unroll
        for (int i = 0; i < 12; ++i) {
            float4 v = s4[i];
            fx[4 * i]     = v.x; fx[4 * i + 1] = v.y;
            fx[4 * i + 2] = v.z; fx[4 * i + 3] = v.w;
        }
    }

    float r[48];
#pragma unroll
    for (int j = 0; j < 8; ++j) {
        const uint4 v = ws[((size_t)b * 1024 + tile * 8 + j) * 64 + k];
#pragma unroll
        for (int h = 0; h < 2; ++h) {
            const int t = 2 * j + h;
            const float sx = h ? up16hi(v.x) : up16lo(v.x);
            const float sy = h ? up16hi(v.y) : up16lo(v.y);
            const float sv = h ? up16hi(v.z) : up16lo(v.z);
            const float pm = fmaf(mv[0], fx[3 * t],
                             fmaf(mv[1], fx[3 * t + 1], mv[2] * fx[3 * t + 2]));
#pragma unroll
            for (int o = 0; o < 3; ++o) {
                const float A = fmaf(spp[o][0], sx,
                                fmaf(spp[o][1], sy, spp[o][2] * sv));
                r[3 * t + o] = fmaf(pm, so[o], A);
            }
        }
    }
#pragma unroll
    for (int v = 0; v < 48; ++v) r[v] = wave_sum63(r[v]);
    if (k == 63) {
        float4* o4 = reinterpret_cast<float4*>(
            out + (size_t)b * (kS * 3) + tile * 48);
#pragma unroll
        for (int i = 0; i < 12; ++i)
            o4[i] = make_float4(r[4 * i], r[4 * i + 1],
                                r[4 * i + 2], r[4 * i + 3]);
    }
}

// ================== Fallback: known-good R2 3-wave kernel ===================
__global__ __launch_bounds__(192, 1)
void j2_pc_kernel(const float* __restrict__ x,
                  const float* __restrict__ W1,
                  const float* __restrict__ W2,
                  float* __restrict__ out)
{
    __shared__ float4 ubuf[2][kT][64];
    __shared__ float4 sgbuf[2][kT][64];

    const int b = blockIdx.x;
    const int w = threadIdx.x >> 6;
    const int k = threadIdx.x & 63;

    const float* xb = x + (size_t)b * (kS * 3);
    float* ob = out + (size_t)b * (kS * 3);

    float e0[3], e1[3], e2[3], lv[3], sp[3][3];
    if (w != 0) {
        float wr[3][3];
#pragma unroll
        for (int j = 0; j < 3; ++j)
#pragma unroll
            for (int f = 0; f < 3; ++f)
                wr[j][f] = W1[(3 * k + j) * 3 + f];
#pragma unroll
        for (int f = 0; f < 3; ++f) {
            e0[f] = kC11 * wr[0][f] + kC12 * wr[1][f];
            e1[f] = kC12 * wr[0][f] + kC11 * wr[1][f];
            e2[f] = kG * wr[2][f];
            lv[f] = kLam * (wr[0][f] + wr[1][f]);
        }
#pragma unroll
        for (int o = 0; o < 3; ++o)
#pragma unroll
            for (int j = 0; j < 3; ++j) {
                float v = W2[o * kLs + 3 * k + j];
                sp[o][j] = log1pf(expf(v));
            }
    }

    float sg0 = 0.f, sg1 = 0.f, sg2 = 0.f, szz = 0.f;
    float y = kSy0;
    const int tlo = (w == 2) ? 8 : 0;
    constexpr float kInv3GH = 1.0f / (3.0f * kG + kH);
    constexpr float k3G = 3.0f * kG;

    for (int phase = 0; phase <= kNBLK + 1; ++phase) {
        if (w == 0) {
            if (phase >= 1 && phase <= kNBLK) {
                const int blk = phase - 1, pb = blk & 1;
                float4 u[kT];
#pragma unroll
                for (int t = 0; t < kT; ++t) u[t] = ubuf[pb][t][k];
#pragma unroll
                for (int t = 0; t < kT; ++t) {
                    const float t0 = sg0 + u[t].x;
                    const float t1 = sg1 + u[t].y;
                    const float t2 = sg2 + u[t].z;
                    const float tz = szz + u[t].w;
                    const float pm  = (t0 + t1 + tz) * (1.0f / 3.0f);
                    const float dxx = t0 - pm, dyy = t1 - pm, dzz = tz - pm;
                    const float sa  = fmaf(dxx, dxx, dyy * dyy);
                    const float sb  = fmaf(dzz, dzz, (2.0f * t2) * t2);
                    const float q2  = fmaf(1.5f, sa + sb, 1e-12f);
                    const float qq  = __builtin_amdgcn_sqrtf(q2);
                    const float rq  = __builtin_amdgcn_rcpf(qq);
                    const float f   = qq - y;
                    const float dg  = (f > 0.0f) ? f * kInv3GH : 0.0f;
                    y = fmaf(kH, dg, y);
                    const float fac = fmaf(-(k3G * dg), rq, 1.0f);
                    sg0 = fmaf(fac, dxx, pm);
                    sg1 = fmaf(fac, dyy, pm);
                    sg2 = fac * t2;
                    szz = fmaf(fac, dzz, pm);
                    sgbuf[pb][t][k] = make_float4(sg0, sg1, sg2, 0.f);
                }
            }
        } else {
            if (phase < kNBLK) {
                const int p = phase, pb = p & 1;
                float xv[28];
                if (w == 1) {
                    if (p == 0) {
                        xv[0] = xv[1] = xv[2] = xv[3] = 0.f;
                        const float4* s4 = reinterpret_cast<const float4*>(xb);
#pragma unroll
                        for (int i = 0; i < 6; ++i) {
                            float4 v = s4[i];
                            xv[4 + 4 * i] = v.x; xv[5 + 4 * i] = v.y;
                            xv[6 + 4 * i] = v.z; xv[7 + 4 * i] = v.w;
                        }
                    } else {
                        const float4* s4 =
                            reinterpret_cast<const float4*>(xb + p * 48 - 4);
#pragma unroll
                        for (int i = 0; i < 7; ++i) {
                            float4 v = s4[i];
                            xv[4 * i]     = v.x; xv[4 * i + 1] = v.y;
                            xv[4 * i + 2] = v.z; xv[4 * i + 3] = v.w;
                        }
                    }
                } else {
                    const float4* s4 =
                        reinterpret_cast<const float4*>(xb + p * 48 + 20);
#pragma unroll
                    for (int i = 0; i < 7; ++i) {
                        float4 v = s4[i];
                        xv[4 * i]     = v.x; xv[4 * i + 1] = v.y;
                        xv[4 * i + 2] = v.z; xv[4 * i + 3] = v.w;
                    }
                }
                const int tbase = (w == 2) ? 8 : 0;
#pragma unroll
                for (int t = 0; t < 8; ++t) {
                    const float dx0 = xv[3 * t + 4] - xv[3 * t + 1];
                    const float dx1 = xv[3 * t + 5] - xv[3 * t + 2];
                    const float dx2 = xv[3 * t + 6] - xv[3 * t + 3];
                    float4 u;
                    u.x = fmaf(e0[0], dx0, fmaf(e0[1], dx1, e0[2] * dx2));
                    u.y = fmaf(e1[0], dx0, fmaf(e1[1], dx1, e1[2] * dx2));
                    u.z = fmaf(e2[0], dx0, fmaf(e2[1], dx1, e2[2] * dx2));
                    u.w = fmaf(lv[0], dx0, fmaf(lv[1], dx1, lv[2] * dx2));
                    ubuf[pb][tbase + t][k] = u;
                }
            }
            if (phase >= 2) {
                const int q = phase - 2, qb = q & 1;
                const int tbase = tlo;
                float r[24];
#pragma unroll
                for (int t = 0; t < 8; ++t) {
                    float4 s = sgbuf[qb][tbase + t][k];
                    r[3 * t]     = fmaf(sp[0][0], s.x, fmaf(sp[0][1], s.y, sp[0][2] * s.z));
                    r[3 * t + 1] = fmaf(sp[1][0], s.x, fmaf(sp[1][1], s.y, sp[1][2] * s.z));
                    r[3 * t + 2] = fmaf(sp[2][0], s.x, fmaf(sp[2][1], s.y, sp[2][2] * s.z));
                }
#pragma unroll
                for (int v = 0; v < 24; ++v) r[v] = wave_sum63(r[v]);
                if (k == 63) {
                    float4* o4 = reinterpret_cast<float4*>(ob + q * 48 + tbase * 3);
#pragma unroll
                    for (int i = 0; i < 6; ++i)
                        o4[i] = make_float4(r[4 * i], r[4 * i + 1],
                                            r[4 * i + 2], r[4 * i + 3]);
                }
            }
        }
        __syncthreads();
    }
}

extern "C" void kernel_launch(void* const* d_in, const int* in_sizes, int n_in,
                              void* d_out, int out_size, void* d_ws, size_t ws_size,
                              hipStream_t stream) {
    const float* x  = (const float*)d_in[0];   // (128, 2048, 3)
    const float* W1 = (const float*)d_in[1];   // (192, 3)
    const float* W2 = (const float*)d_in[2];   // (3, 192)
    float* out = (float*)d_out;                // (128, 2048, 3)

    const size_t need = (size_t)128 * 1024 * 64 * sizeof(uint4);  // 128 MiB
    if (ws_size >= need) {
        j2_dx<<<dim3(1024), dim3(256), 0, stream>>>(x);
        j2_scan2l<<<dim3(256), dim3(64), 0, stream>>>(W1, (uint2*)d_ws);
        j2_out_einsum<<<dim3(128, 128), dim3(64), 0, stream>>>(
            x, W1, W2, (const uint4*)d_ws, out);
    } else {
        j2_pc_kernel<<<dim3(128), dim3(192), 0, stream>>>(x, W1, W2, out);
    }
}

// Round 14
// 167.305 us; speedup vs baseline: 2.0304x; 1.0068x over previous
//
#include <hip/hip_runtime.h>
#include <cmath>

namespace {
constexpr float kE   = 3130.0f;
constexpr float kNu  = 0.37f;
constexpr float kSy0 = 64.8f;
constexpr float kH   = 100.0f;
constexpr float kG   = kE / (2.0f * (1.0f + kNu));
constexpr float kLam = kE * kNu / ((1.0f + kNu) * (1.0f - 2.0f * kNu));
constexpr float kC   = kE / ((1.0f + kNu) * (1.0f - 2.0f * kNu));
constexpr float kC11 = kC * (1.0f - kNu);
constexpr float kC12 = kC * kNu;
constexpr float kC2  = 3.0f * kG / (3.0f * kG + kH);  // 3G/(3G+H)
constexpr float kC3  = kH / (3.0f * kG + kH);         // 1 - kC2
constexpr int kS  = 2048;
constexpr int kT  = 16;
constexpr int kNBLK = kS / kT;   // 128
constexpr int kLs = 192;
constexpr float kSq15  = 1.224744871391589f;  // sqrt(1.5)
constexpr float kSq3   = 1.732050807568877f;  // sqrt(3)
constexpr float kISq15 = 1.0f / kSq15;
constexpr float kISq3  = 1.0f / kSq3;
// compact ws: per (b, t2) a row of 192 dwords: [c0: 64 chains][c1][c2]
constexpr int kRow = 192;                       // dwords per (b,t2)
constexpr size_t kBStride = (size_t)1024 * kRow; // dwords per batch
}

typedef __fp16 half2_t __attribute__((ext_vector_type(2)));
typedef float f4_t __attribute__((ext_vector_type(4)));

__device__ __forceinline__ unsigned pk16(float a, float b) {
    half2_t h = __builtin_amdgcn_cvt_pkrtz(a, b);
    return __builtin_bit_cast(unsigned, h);
}
__device__ __forceinline__ float up16lo(unsigned u) {
    half2_t h = __builtin_bit_cast(half2_t, u);
    return (float)h.x;
}
__device__ __forceinline__ float up16hi(unsigned u) {
    half2_t h = __builtin_bit_cast(half2_t, u);
    return (float)h.y;
}

template<int CTRL, int RM, int BM>
__device__ __forceinline__ float dppmov(float v) {
    return __int_as_float(
        __builtin_amdgcn_update_dpp(0, __float_as_int(v), CTRL, RM, BM, false));
}
// wave64 sum, result in lane 63 (row_shr + row_bcast chain, VALU-only)
__device__ __forceinline__ float wave_sum63(float v) {
    v += dppmov<0x111, 0xf, 0xf>(v);
    v += dppmov<0x112, 0xf, 0xf>(v);
    v += dppmov<0x114, 0xf, 0xf>(v);
    v += dppmov<0x118, 0xf, 0xf>(v);
    v += dppmov<0x142, 0xa, 0xf>(v);
    v += dppmov<0x143, 0xc, 0xf>(v);
    return v;
}
// quad_perm DPP move (4-lane group reduce helper)
template<int CTRL>
__device__ __forceinline__ float qdpp(float v) {
    return __int_as_float(
        __builtin_amdgcn_update_dpp(0, __float_as_int(v), CTRL, 0xF, 0xF, true));
}

// pre-differenced strain-driver dx stream: (b, t) -> 3 floats
__device__ __align__(16) float g_dx[128 * 2048 * 3];   // 3.1 MB

// ===================== Kernel A: dx pre-difference ==========================
__global__ __launch_bounds__(256, 4)
void j2_dx(const float* __restrict__ x)
{
    const int gid = blockIdx.x * 256 + threadIdx.x;   // (b,t), 0..262143
    const int t = gid & 2047;
    const float* xe = x + (size_t)gid * 3;
    const float a0 = xe[0], a1 = xe[1], a2 = xe[2];
    float p0 = 0.f, p1 = 0.f, p2 = 0.f;
    if (t != 0) { p0 = xe[-3]; p1 = xe[-2]; p2 = xe[-1]; }
    float* o = g_dx + (size_t)gid * 3;
    o[0] = a0 - p0; o[1] = a1 - p1; o[2] = a2 - p2;
}

// ================ Kernel B: lane-parallel component scan ====================
// Grid (128 b, 4 quarter) x 64 — R9's proven structure. Lane = 4*kc + c,
// component c in {s0h, s1h, s2h, szh}. q2 = quad-DPP sum of squares.
// Stores: only c<3 lanes store (szh = -(s0h+s1h) is redundant for output) ->
// compact c-major ws rows of 192 dwords, 100.7 MB total (was 134).
__global__ __launch_bounds__(64, 1)
void j2_scan4(const float* __restrict__ W1, unsigned* __restrict__ ws32)
{
    const int b   = blockIdx.x;
    const int qtr = blockIdx.y;
    const int ln  = threadIdx.x;
    const int kc  = ln >> 2;            // local chain 0..15
    const int c   = ln & 3;             // component
    const int kg  = qtr * 16 + kc;      // chain within batch 0..63

    // own component's projection vector g[3]
    float gv[3];
#pragma unroll
    for (int f = 0; f < 3; ++f) {
        const float w0 = W1[(3 * kg + 0) * 3 + f];
        const float w1 = W1[(3 * kg + 1) * 3 + f];
        const float w2 = W1[(3 * kg + 2) * 3 + f];
        const float e0 = kC11 * w0 + kC12 * w1;
        const float e1 = kC12 * w0 + kC11 * w1;
        const float lv = kLam * (w0 + w1);
        const float g0 = kSq15 * (2.0f * e0 - e1 - lv) * (1.0f / 3.0f);
        const float g1 = kSq15 * (2.0f * e1 - e0 - lv) * (1.0f / 3.0f);
        const float g2 = kSq3 * kG * w2;
        const float gz = -(g0 + g1);
        gv[f] = (c == 0) ? g0 : (c == 1) ? g1 : (c == 2) ? g2 : gz;
    }

    const float* db = g_dx + (size_t)b * (kS * 3);
    // compact layout: dword idx = b*kBStride + t2*kRow + c*64 + kg
    unsigned* wsb = ws32 + (size_t)b * kBStride + c * 64 + kg;
    const bool doStore = (c < 3);

    float s = 0.f, y = kSy0, c2y = kC2 * kSy0;

    auto loadw = [&](f4_t* dst, int p) {
        const f4_t* s4 = reinterpret_cast<const f4_t*>(db + p * 48);
#pragma unroll
        for (int i = 0; i < 12; ++i) dst[i] = s4[i];
    };

    auto body = [&](const f4_t* Wd, int p) {
        float u[kT];
#pragma unroll
        for (int t = 0; t < kT; ++t) {
            const float d0 = Wd[(3 * t + 0) >> 2][(3 * t + 0) & 3];
            const float d1 = Wd[(3 * t + 1) >> 2][(3 * t + 1) & 3];
            const float d2 = Wd[(3 * t + 2) >> 2][(3 * t + 2) & 3];
            u[t] = fmaf(gv[0], d0, fmaf(gv[1], d1, gv[2] * d2));
        }
        float se = 0.f;
#pragma unroll
        for (int t = 0; t < kT; ++t) {
            const float st = s + u[t];
            float pp = fmaf(st, st, 2.5e-13f);      // 4 lanes -> +1e-12 total
            pp += qdpp<0xB1>(pp);                   // quad_perm [1,0,3,2]
            pp += qdpp<0x4E>(pp);                   // quad_perm [2,3,0,1]
            const float rq  = __builtin_amdgcn_rsqf(pp);
            const float fac = fminf(fmaf(c2y, rq, kC3), 1.0f);
            s = fac * st;
            const float qv = pp * rq;
            y = fmaxf(y, fmaf(kC3, qv, c2y));
            c2y = kC2 * y;
            if ((t & 1) == 0) {
                se = s;
            } else {
                if (doStore)
                    wsb[(size_t)(p * 8 + (t >> 1)) * kRow] = pk16(se, s);
            }
        }
    };

    f4_t A[12], B[12];
    loadw(A, 0);
    for (int p = 0; p < kNBLK; p += 2) {
        loadw(B, p + 1);
        body(A, p);
        if (p + 2 < kNBLK) loadw(A, p + 2);
        body(B, p + 1);
    }
}

// ========================= Kernel C: output einsum ==========================
// Lane k = chain k. Per (b, t2): row of 192 dwords [c0][c1][c2]; each c-read
// is a fully-coalesced 256 B wave-load.
__global__ __launch_bounds__(64, 1)
void j2_out_einsum(const float* __restrict__ x,
                   const float* __restrict__ W1,
                   const float* __restrict__ W2,
                   const unsigned* __restrict__ ws32,
                   float* __restrict__ out)
{
    const int b = blockIdx.x;
    const int tile = blockIdx.y;
    const int k = threadIdx.x;

    float wr[3][3];
#pragma unroll
    for (int j = 0; j < 3; ++j)
#pragma unroll
        for (int f = 0; f < 3; ++f)
            wr[j][f] = W1[(3 * k + j) * 3 + f];
    float mv[3];
#pragma unroll
    for (int f = 0; f < 3; ++f) {
        const float e0 = kC11 * wr[0][f] + kC12 * wr[1][f];
        const float e1 = kC12 * wr[0][f] + kC11 * wr[1][f];
        const float lv = kLam * (wr[0][f] + wr[1][f]);
        mv[f] = (e0 + e1 + lv) * (1.0f / 3.0f);
    }
    float spp[3][3], so[3];
#pragma unroll
    for (int o = 0; o < 3; ++o) {
        const float a0 = __logf(1.0f + __expf(W2[o * kLs + 3 * k + 0]));
        const float a1 = __logf(1.0f + __expf(W2[o * kLs + 3 * k + 1]));
        const float a2 = __logf(1.0f + __expf(W2[o * kLs + 3 * k + 2]));
        spp[o][0] = a0 * kISq15;
        spp[o][1] = a1 * kISq15;
        spp[o][2] = a2 * kISq3;
        so[o] = a0 + a1;
    }

    float fx[48];
    {
        const float4* s4 = reinterpret_cast<const float4*>(
            x + (size_t)b * (kS * 3) + tile * 48);
#pragma unroll
        for (int i = 0; i < 12; ++i) {
            float4 v = s4[i];
            fx[4 * i]     = v.x; fx[4 * i + 1] = v.y;
            fx[4 * i + 2] = v.z; fx[4 * i + 3] = v.w;
        }
    }

    const unsigned* wb = ws32 + (size_t)b * kBStride + (size_t)tile * 8 * kRow;

    float r[48];
#pragma unroll
    for (int j = 0; j < 8; ++j) {
        const unsigned u0 = wb[j * kRow + k];
        const unsigned u1 = wb[j * kRow + 64 + k];
        const unsigned u2 = wb[j * kRow + 128 + k];
#pragma unroll
        for (int h = 0; h < 2; ++h) {
            const int t = 2 * j + h;
            const float sx = h ? up16hi(u0) : up16lo(u0);
            const float sy = h ? up16hi(u1) : up16lo(u1);
            const float sv = h ? up16hi(u2) : up16lo(u2);
            const float pm = fmaf(mv[0], fx[3 * t],
                             fmaf(mv[1], fx[3 * t + 1], mv[2] * fx[3 * t + 2]));
#pragma unroll
            for (int o = 0; o < 3; ++o) {
                const float A = fmaf(spp[o][0], sx,
                                fmaf(spp[o][1], sy, spp[o][2] * sv));
                r[3 * t + o] = fmaf(pm, so[o], A);
            }
        }
    }
#pragma unroll
    for (int v = 0; v < 48; ++v) r[v] = wave_sum63(r[v]);
    if (k == 63) {
        float4* o4 = reinterpret_cast<float4*>(
            out + (size_t)b * (kS * 3) + tile * 48);
#pragma unroll
        for (int i = 0; i < 12; ++i)
            o4[i] = make_float4(r[4 * i], r[4 * i + 1],
                                r[4 * i + 2], r[4 * i + 3]);
    }
}

// ================== Fallback: known-good R2 3-wave kernel ===================
__global__ __launch_bounds__(192, 1)
void j2_pc_kernel(const float* __restrict__ x,
                  const float* __restrict__ W1,
                  const float* __restrict__ W2,
                  float* __restrict__ out)
{
    __shared__ float4 ubuf[2][kT][64];
    __shared__ float4 sgbuf[2][kT][64];

    const int b = blockIdx.x;
    const int w = threadIdx.x >> 6;
    const int k = threadIdx.x & 63;

    const float* xb = x + (size_t)b * (kS * 3);
    float* ob = out + (size_t)b * (kS * 3);

    float e0[3], e1[3], e2[3], lv[3], sp[3][3];
    if (w != 0) {
        float wr[3][3];
#pragma unroll
        for (int j = 0; j < 3; ++j)
#pragma unroll
            for (int f = 0; f < 3; ++f)
                wr[j][f] = W1[(3 * k + j) * 3 + f];
#pragma unroll
        for (int f = 0; f < 3; ++f) {
            e0[f] = kC11 * wr[0][f] + kC12 * wr[1][f];
            e1[f] = kC12 * wr[0][f] + kC11 * wr[1][f];
            e2[f] = kG * wr[2][f];
            lv[f] = kLam * (wr[0][f] + wr[1][f]);
        }
#pragma unroll
        for (int o = 0; o < 3; ++o)
#pragma unroll
            for (int j = 0; j < 3; ++j) {
                float v = W2[o * kLs + 3 * k + j];
                sp[o][j] = log1pf(expf(v));
            }
    }

    float sg0 = 0.f, sg1 = 0.f, sg2 = 0.f, szz = 0.f;
    float y = kSy0;
    const int tlo = (w == 2) ? 8 : 0;
    constexpr float kInv3GH = 1.0f / (3.0f * kG + kH);
    constexpr float k3G = 3.0f * kG;

    for (int phase = 0; phase <= kNBLK + 1; ++phase) {
        if (w == 0) {
            if (phase >= 1 && phase <= kNBLK) {
                const int blk = phase - 1, pb = blk & 1;
                float4 u[kT];
#pragma unroll
                for (int t = 0; t < kT; ++t) u[t] = ubuf[pb][t][k];
#pragma unroll
                for (int t = 0; t < kT; ++t) {
                    const float t0 = sg0 + u[t].x;
                    const float t1 = sg1 + u[t].y;
                    const float t2 = sg2 + u[t].z;
                    const float tz = szz + u[t].w;
                    const float pm  = (t0 + t1 + tz) * (1.0f / 3.0f);
                    const float dxx = t0 - pm, dyy = t1 - pm, dzz = tz - pm;
                    const float sa  = fmaf(dxx, dxx, dyy * dyy);
                    const float sb  = fmaf(dzz, dzz, (2.0f * t2) * t2);
                    const float q2  = fmaf(1.5f, sa + sb, 1e-12f);
                    const float qq  = __builtin_amdgcn_sqrtf(q2);
                    const float rq  = __builtin_amdgcn_rcpf(qq);
                    const float f   = qq - y;
                    const float dg  = (f > 0.0f) ? f * kInv3GH : 0.0f;
                    y = fmaf(kH, dg, y);
                    const float fac = fmaf(-(k3G * dg), rq, 1.0f);
                    sg0 = fmaf(fac, dxx, pm);
                    sg1 = fmaf(fac, dyy, pm);
                    sg2 = fac * t2;
                    szz = fmaf(fac, dzz, pm);
                    sgbuf[pb][t][k] = make_float4(sg0, sg1, sg2, 0.f);
                }
            }
        } else {
            if (phase < kNBLK) {
                const int p = phase, pb = p & 1;
                float xv[28];
                if (w == 1) {
                    if (p == 0) {
                        xv[0] = xv[1] = xv[2] = xv[3] = 0.f;
                        const float4* s4 = reinterpret_cast<const float4*>(xb);
#pragma unroll
                        for (int i = 0; i < 6; ++i) {
                            float4 v = s4[i];
                            xv[4 + 4 * i] = v.x; xv[5 + 4 * i] = v.y;
                            xv[6 + 4 * i] = v.z; xv[7 + 4 * i] = v.w;
                        }
                    } else {
                        const float4* s4 =
                            reinterpret_cast<const float4*>(xb + p * 48 - 4);
#pragma unroll
                        for (int i = 0; i < 7; ++i) {
                            float4 v = s4[i];
                            xv[4 * i]     = v.x; xv[4 * i + 1] = v.y;
                            xv[4 * i + 2] = v.z; xv[4 * i + 3] = v.w;
                        }
                    }
                } else {
                    const float4* s4 =
                        reinterpret_cast<const float4*>(xb + p * 48 + 20);
#pragma unroll
                    for (int i = 0; i < 7; ++i) {
                        float4 v = s4[i];
                        xv[4 * i]     = v.x; xv[4 * i + 1] = v.y;
                        xv[4 * i + 2] = v.z; xv[4 * i + 3] = v.w;
                    }
                }
                const int tbase = (w == 2) ? 8 : 0;
#pragma unroll
                for (int t = 0; t < 8; ++t) {
                    const float dx0 = xv[3 * t + 4] - xv[3 * t + 1];
                    const float dx1 = xv[3 * t + 5] - xv[3 * t + 2];
                    const float dx2 = xv[3 * t + 6] - xv[3 * t + 3];
                    float4 u;
                    u.x = fmaf(e0[0], dx0, fmaf(e0[1], dx1, e0[2] * dx2));
                    u.y = fmaf(e1[0], dx0, fmaf(e1[1], dx1, e1[2] * dx2));
                    u.z = fmaf(e2[0], dx0, fmaf(e2[1], dx1, e2[2] * dx2));
                    u.w = fmaf(lv[0], dx0, fmaf(lv[1], dx1, lv[2] * dx2));
                    ubuf[pb][tbase + t][k] = u;
                }
            }
            if (phase >= 2) {
                const int q = phase - 2, qb = q & 1;
                const int tbase = tlo;
                float r[24];
#pragma unroll
                for (int t = 0; t < 8; ++t) {
                    float4 s = sgbuf[qb][tbase + t][k];
                    r[3 * t]     = fmaf(sp[0][0], s.x, fmaf(sp[0][1], s.y, sp[0][2] * s.z));
                    r[3 * t + 1] = fmaf(sp[1][0], s.x, fmaf(sp[1][1], s.y, sp[1][2] * s.z));
                    r[3 * t + 2] = fmaf(sp[2][0], s.x, fmaf(sp[2][1], s.y, sp[2][2] * s.z));
                }
#pragma unroll
                for (int v = 0; v < 24; ++v) r[v] = wave_sum63(r[v]);
                if (k == 63) {
                    float4* o4 = reinterpret_cast<float4*>(ob + q * 48 + tbase * 3);
#pragma unroll
                    for (int i = 0; i < 6; ++i)
                        o4[i] = make_float4(r[4 * i], r[4 * i + 1],
                                            r[4 * i + 2], r[4 * i + 3]);
                }
            }
        }
        __syncthreads();
    }
}

extern "C" void kernel_launch(void* const* d_in, const int* in_sizes, int n_in,
                              void* d_out, int out_size, void* d_ws, size_t ws_size,
                              hipStream_t stream) {
    const float* x  = (const float*)d_in[0];   // (128, 2048, 3)
    const float* W1 = (const float*)d_in[1];   // (192, 3)
    const float* W2 = (const float*)d_in[2];   // (3, 192)
    float* out = (float*)d_out;                // (128, 2048, 3)

    const size_t need = (size_t)128 * kBStride * sizeof(unsigned);  // 100.7 MB
    if (ws_size >= need) {
        j2_dx<<<dim3(1024), dim3(256), 0, stream>>>(x);
        j2_scan4<<<dim3(128, 4), dim3(64), 0, stream>>>(W1, (unsigned*)d_ws);
        j2_out_einsum<<<dim3(128, 128), dim3(64), 0, stream>>>(
            x, W1, W2, (const unsigned*)d_ws, out);
    } else {
        j2_pc_kernel<<<dim3(128), dim3(192), 0, stream>>>(x, W1, W2, out);
    }
}

// Round 15
// 149.251 us; speedup vs baseline: 2.2760x; 1.1210x over previous
//
#include <hip/hip_runtime.h>
#include <cmath>

namespace {
constexpr float kE   = 3130.0f;
constexpr float kNu  = 0.37f;
constexpr float kSy0 = 64.8f;
constexpr float kH   = 100.0f;
constexpr float kG   = kE / (2.0f * (1.0f + kNu));
constexpr float kLam = kE * kNu / ((1.0f + kNu) * (1.0f - 2.0f * kNu));
constexpr float kC   = kE / ((1.0f + kNu) * (1.0f - 2.0f * kNu));
constexpr float kC11 = kC * (1.0f - kNu);
constexpr float kC12 = kC * kNu;
constexpr float kC2  = 3.0f * kG / (3.0f * kG + kH);  // 3G/(3G+H)
constexpr float kC3  = kH / (3.0f * kG + kH);         // 1 - kC2
constexpr int kS  = 2048;
constexpr int kT  = 16;
constexpr int kNBLK = kS / kT;   // 128
constexpr int kLs = 192;
constexpr float kSq15  = 1.224744871391589f;  // sqrt(1.5)
constexpr float kSq3   = 1.732050807568877f;  // sqrt(3)
constexpr float kISq15 = 1.0f / kSq15;
constexpr float kISq3  = 1.0f / kSq3;
}

typedef __fp16 half2_t __attribute__((ext_vector_type(2)));
typedef float f4_t __attribute__((ext_vector_type(4)));

__device__ __forceinline__ unsigned pk16(float a, float b) {
    half2_t h = __builtin_amdgcn_cvt_pkrtz(a, b);
    return __builtin_bit_cast(unsigned, h);
}
__device__ __forceinline__ float up16lo(unsigned u) {
    half2_t h = __builtin_bit_cast(half2_t, u);
    return (float)h.x;
}
__device__ __forceinline__ float up16hi(unsigned u) {
    half2_t h = __builtin_bit_cast(half2_t, u);
    return (float)h.y;
}

template<int CTRL, int RM, int BM>
__device__ __forceinline__ float dppmov(float v) {
    return __int_as_float(
        __builtin_amdgcn_update_dpp(0, __float_as_int(v), CTRL, RM, BM, false));
}
// wave64 sum, result in lane 63 (row_shr + row_bcast chain, VALU-only)
__device__ __forceinline__ float wave_sum63(float v) {
    v += dppmov<0x111, 0xf, 0xf>(v);
    v += dppmov<0x112, 0xf, 0xf>(v);
    v += dppmov<0x114, 0xf, 0xf>(v);
    v += dppmov<0x118, 0xf, 0xf>(v);
    v += dppmov<0x142, 0xa, 0xf>(v);
    v += dppmov<0x143, 0xc, 0xf>(v);
    return v;
}
// quad_perm DPP move (4-lane group reduce helper)
template<int CTRL>
__device__ __forceinline__ float qdpp(float v) {
    return __int_as_float(
        __builtin_amdgcn_update_dpp(0, __float_as_int(v), CTRL, 0xF, 0xF, true));
}

// pre-differenced strain-driver dx stream: (b, t) -> 3 floats
__device__ __align__(16) float g_dx[128 * 2048 * 3];   // 3.1 MB

// ===================== Kernel A: dx pre-difference ==========================
__global__ __launch_bounds__(256, 4)
void j2_dx(const float* __restrict__ x)
{
    const int gid = blockIdx.x * 256 + threadIdx.x;   // (b,t), 0..262143
    const int t = gid & 2047;
    const float* xe = x + (size_t)gid * 3;
    const float a0 = xe[0], a1 = xe[1], a2 = xe[2];
    float p0 = 0.f, p1 = 0.f, p2 = 0.f;
    if (t != 0) { p0 = xe[-3]; p1 = xe[-2]; p2 = xe[-1]; }
    float* o = g_dx + (size_t)gid * 3;
    o[0] = a0 - p0; o[1] = a1 - p1; o[2] = a2 - p2;
}

// ================ Kernel B: lane-parallel component scan ====================
// Grid (128 b, 4 quarter) x 64. 4 lanes per chain: lane = 4*kc + c, component
// c in {s0h, s1h, s2h, szh} (hat = sqrt-scaled deviatoric). q2 = quad-DPP sum
// of per-lane squares. Measured floor: ~130 cyc/step (66 issue + 64 chain
// latency); all structural variations (R10-R14) regressed.
__global__ __launch_bounds__(64, 1)
void j2_scan4(const float* __restrict__ W1, unsigned* __restrict__ ws32)
{
    const int b   = blockIdx.x;
    const int qtr = blockIdx.y;
    const int ln  = threadIdx.x;
    const int kc  = ln >> 2;            // local chain 0..15
    const int c   = ln & 3;             // component
    const int kg  = qtr * 16 + kc;      // chain within batch 0..63

    // own component's projection vector g[3]
    float gv[3];
#pragma unroll
    for (int f = 0; f < 3; ++f) {
        const float w0 = W1[(3 * kg + 0) * 3 + f];
        const float w1 = W1[(3 * kg + 1) * 3 + f];
        const float w2 = W1[(3 * kg + 2) * 3 + f];
        const float e0 = kC11 * w0 + kC12 * w1;
        const float e1 = kC12 * w0 + kC11 * w1;
        const float lv = kLam * (w0 + w1);
        const float g0 = kSq15 * (2.0f * e0 - e1 - lv) * (1.0f / 3.0f);
        const float g1 = kSq15 * (2.0f * e1 - e0 - lv) * (1.0f / 3.0f);
        const float g2 = kSq3 * kG * w2;
        const float gz = -(g0 + g1);
        gv[f] = (c == 0) ? g0 : (c == 1) ? g1 : (c == 2) ? g2 : gz;
    }

    const float* db = g_dx + (size_t)b * (kS * 3);
    unsigned* wsb = ws32 + (size_t)b * 1024 * 256 + qtr * 64 + ln;

    float s = 0.f, y = kSy0, c2y = kC2 * kSy0;

    auto loadw = [&](f4_t* dst, int p) {
        const f4_t* s4 = reinterpret_cast<const f4_t*>(db + p * 48);
#pragma unroll
        for (int i = 0; i < 12; ++i) dst[i] = s4[i];
    };

    auto body = [&](const f4_t* Wd, int p) {
        // off-chain: projection increments for all 16 steps
        float u[kT];
#pragma unroll
        for (int t = 0; t < kT; ++t) {
            const float d0 = Wd[(3 * t + 0) >> 2][(3 * t + 0) & 3];
            const float d1 = Wd[(3 * t + 1) >> 2][(3 * t + 1) & 3];
            const float d2 = Wd[(3 * t + 2) >> 2][(3 * t + 2) & 3];
            u[t] = fmaf(gv[0], d0, fmaf(gv[1], d1, gv[2] * d2));
        }
        float se = 0.f;
#pragma unroll
        for (int t = 0; t < kT; ++t) {
            const float st = s + u[t];
            float pp = fmaf(st, st, 2.5e-13f);      // 4 lanes -> +1e-12 total
            pp += qdpp<0xB1>(pp);                   // quad_perm [1,0,3,2]
            pp += qdpp<0x4E>(pp);                   // quad_perm [2,3,0,1]
            const float rq  = __builtin_amdgcn_rsqf(pp);
            const float fac = fminf(fmaf(c2y, rq, kC3), 1.0f);
            s = fac * st;
            const float qv = pp * rq;
            y = fmaxf(y, fmaf(kC3, qv, c2y));
            c2y = kC2 * y;
            if ((t & 1) == 0) {
                se = s;
            } else {
                wsb[(size_t)(p * 8 + (t >> 1)) * 256] = pk16(se, s);
            }
        }
    };

    f4_t A[12], B[12];
    loadw(A, 0);
    for (int p = 0; p < kNBLK; p += 2) {
        loadw(B, p + 1);
        body(A, p);
        if (p + 2 < kNBLK) loadw(A, p + 2);
        body(B, p + 1);
    }
}

// ========================= Kernel C: output einsum ==========================
// Lane k = chain k. uint4 per (b, t2, chain): x=pk(s0 even,odd) y=pk(s1)
// z=pk(s2) w=pk(sz, unused).
__global__ __launch_bounds__(64, 1)
void j2_out_einsum(const float* __restrict__ x,
                   const float* __restrict__ W1,
                   const float* __restrict__ W2,
                   const uint4* __restrict__ ws,
                   float* __restrict__ out)
{
    const int b = blockIdx.x;
    const int tile = blockIdx.y;
    const int k = threadIdx.x;

    float wr[3][3];
#pragma unroll
    for (int j = 0; j < 3; ++j)
#pragma unroll
        for (int f = 0; f < 3; ++f)
            wr[j][f] = W1[(3 * k + j) * 3 + f];
    float mv[3];
#pragma unroll
    for (int f = 0; f < 3; ++f) {
        const float e0 = kC11 * wr[0][f] + kC12 * wr[1][f];
        const float e1 = kC12 * wr[0][f] + kC11 * wr[1][f];
        const float lv = kLam * (wr[0][f] + wr[1][f]);
        mv[f] = (e0 + e1 + lv) * (1.0f / 3.0f);
    }
    float spp[3][3], so[3];
#pragma unroll
    for (int o = 0; o < 3; ++o) {
        const float a0 = __logf(1.0f + __expf(W2[o * kLs + 3 * k + 0]));
        const float a1 = __logf(1.0f + __expf(W2[o * kLs + 3 * k + 1]));
        const float a2 = __logf(1.0f + __expf(W2[o * kLs + 3 * k + 2]));
        spp[o][0] = a0 * kISq15;
        spp[o][1] = a1 * kISq15;
        spp[o][2] = a2 * kISq3;
        so[o] = a0 + a1;
    }

    // x for mean stress (lane-uniform broadcast loads)
    float fx[48];
    {
        const float4* s4 = reinterpret_cast<const float4*>(
            x + (size_t)b * (kS * 3) + tile * 48);
#pragma unroll
        for (int i = 0; i < 12; ++i) {
            float4 v = s4[i];
            fx[4 * i]     = v.x; fx[4 * i + 1] = v.y;
            fx[4 * i + 2] = v.z; fx[4 * i + 3] = v.w;
        }
    }

    float r[48];
#pragma unroll
    for (int j = 0; j < 8; ++j) {
        const uint4 v = ws[((size_t)b * 1024 + tile * 8 + j) * 64 + k];
#pragma unroll
        for (int h = 0; h < 2; ++h) {
            const int t = 2 * j + h;
            const float sx = h ? up16hi(v.x) : up16lo(v.x);
            const float sy = h ? up16hi(v.y) : up16lo(v.y);
            const float sv = h ? up16hi(v.z) : up16lo(v.z);
            const float pm = fmaf(mv[0], fx[3 * t],
                             fmaf(mv[1], fx[3 * t + 1], mv[2] * fx[3 * t + 2]));
#pragma unroll
            for (int o = 0; o < 3; ++o) {
                const float A = fmaf(spp[o][0], sx,
                                fmaf(spp[o][1], sy, spp[o][2] * sv));
                r[3 * t + o] = fmaf(pm, so[o], A);
            }
        }
    }
#pragma unroll
    for (int v = 0; v < 48; ++v) r[v] = wave_sum63(r[v]);
    if (k == 63) {
        float4* o4 = reinterpret_cast<float4*>(
            out + (size_t)b * (kS * 3) + tile * 48);
#pragma unroll
        for (int i = 0; i < 12; ++i)
            o4[i] = make_float4(r[4 * i], r[4 * i + 1],
                                r[4 * i + 2], r[4 * i + 3]);
    }
}

// ================== Fallback: known-good R2 3-wave kernel ===================
__global__ __launch_bounds__(192, 1)
void j2_pc_kernel(const float* __restrict__ x,
                  const float* __restrict__ W1,
                  const float* __restrict__ W2,
                  float* __restrict__ out)
{
    __shared__ float4 ubuf[2][kT][64];
    __shared__ float4 sgbuf[2][kT][64];

    const int b = blockIdx.x;
    const int w = threadIdx.x >> 6;
    const int k = threadIdx.x & 63;

    const float* xb = x + (size_t)b * (kS * 3);
    float* ob = out + (size_t)b * (kS * 3);

    float e0[3], e1[3], e2[3], lv[3], sp[3][3];
    if (w != 0) {
        float wr[3][3];
#pragma unroll
        for (int j = 0; j < 3; ++j)
#pragma unroll
            for (int f = 0; f < 3; ++f)
                wr[j][f] = W1[(3 * k + j) * 3 + f];
#pragma unroll
        for (int f = 0; f < 3; ++f) {
            e0[f] = kC11 * wr[0][f] + kC12 * wr[1][f];
            e1[f] = kC12 * wr[0][f] + kC11 * wr[1][f];
            e2[f] = kG * wr[2][f];
            lv[f] = kLam * (wr[0][f] + wr[1][f]);
        }
#pragma unroll
        for (int o = 0; o < 3; ++o)
#pragma unroll
            for (int j = 0; j < 3; ++j) {
                float v = W2[o * kLs + 3 * k + j];
                sp[o][j] = log1pf(expf(v));
            }
    }

    float sg0 = 0.f, sg1 = 0.f, sg2 = 0.f, szz = 0.f;
    float y = kSy0;
    const int tlo = (w == 2) ? 8 : 0;
    constexpr float kInv3GH = 1.0f / (3.0f * kG + kH);
    constexpr float k3G = 3.0f * kG;

    for (int phase = 0; phase <= kNBLK + 1; ++phase) {
        if (w == 0) {
            if (phase >= 1 && phase <= kNBLK) {
                const int blk = phase - 1, pb = blk & 1;
                float4 u[kT];
#pragma unroll
                for (int t = 0; t < kT; ++t) u[t] = ubuf[pb][t][k];
#pragma unroll
                for (int t = 0; t < kT; ++t) {
                    const float t0 = sg0 + u[t].x;
                    const float t1 = sg1 + u[t].y;
                    const float t2 = sg2 + u[t].z;
                    const float tz = szz + u[t].w;
                    const float pm  = (t0 + t1 + tz) * (1.0f / 3.0f);
                    const float dxx = t0 - pm, dyy = t1 - pm, dzz = tz - pm;
                    const float sa  = fmaf(dxx, dxx, dyy * dyy);
                    const float sb  = fmaf(dzz, dzz, (2.0f * t2) * t2);
                    const float q2  = fmaf(1.5f, sa + sb, 1e-12f);
                    const float qq  = __builtin_amdgcn_sqrtf(q2);
                    const float rq  = __builtin_amdgcn_rcpf(qq);
                    const float f   = qq - y;
                    const float dg  = (f > 0.0f) ? f * kInv3GH : 0.0f;
                    y = fmaf(kH, dg, y);
                    const float fac = fmaf(-(k3G * dg), rq, 1.0f);
                    sg0 = fmaf(fac, dxx, pm);
                    sg1 = fmaf(fac, dyy, pm);
                    sg2 = fac * t2;
                    szz = fmaf(fac, dzz, pm);
                    sgbuf[pb][t][k] = make_float4(sg0, sg1, sg2, 0.f);
                }
            }
        } else {
            if (phase < kNBLK) {
                const int p = phase, pb = p & 1;
                float xv[28];
                if (w == 1) {
                    if (p == 0) {
                        xv[0] = xv[1] = xv[2] = xv[3] = 0.f;
                        const float4* s4 = reinterpret_cast<const float4*>(xb);
#pragma unroll
                        for (int i = 0; i < 6; ++i) {
                            float4 v = s4[i];
                            xv[4 + 4 * i] = v.x; xv[5 + 4 * i] = v.y;
                            xv[6 + 4 * i] = v.z; xv[7 + 4 * i] = v.w;
                        }
                    } else {
                        const float4* s4 =
                            reinterpret_cast<const float4*>(xb + p * 48 - 4);
#pragma unroll
                        for (int i = 0; i < 7; ++i) {
                            float4 v = s4[i];
                            xv[4 * i]     = v.x; xv[4 * i + 1] = v.y;
                            xv[4 * i + 2] = v.z; xv[4 * i + 3] = v.w;
                        }
                    }
                } else {
                    const float4* s4 =
                        reinterpret_cast<const float4*>(xb + p * 48 + 20);
#pragma unroll
                    for (int i = 0; i < 7; ++i) {
                        float4 v = s4[i];
                        xv[4 * i]     = v.x; xv[4 * i + 1] = v.y;
                        xv[4 * i + 2] = v.z; xv[4 * i + 3] = v.w;
                    }
                }
                const int tbase = (w == 2) ? 8 : 0;
#pragma unroll
                for (int t = 0; t < 8; ++t) {
                    const float dx0 = xv[3 * t + 4] - xv[3 * t + 1];
                    const float dx1 = xv[3 * t + 5] - xv[3 * t + 2];
                    const float dx2 = xv[3 * t + 6] - xv[3 * t + 3];
                    float4 u;
                    u.x = fmaf(e0[0], dx0, fmaf(e0[1], dx1, e0[2] * dx2));
                    u.y = fmaf(e1[0], dx0, fmaf(e1[1], dx1, e1[2] * dx2));
                    u.z = fmaf(e2[0], dx0, fmaf(e2[1], dx1, e2[2] * dx2));
                    u.w = fmaf(lv[0], dx0, fmaf(lv[1], dx1, lv[2] * dx2));
                    ubuf[pb][tbase + t][k] = u;
                }
            }
            if (phase >= 2) {
                const int q = phase - 2, qb = q & 1;
                const int tbase = tlo;
                float r[24];
#pragma unroll
                for (int t = 0; t < 8; ++t) {
                    float4 s = sgbuf[qb][tbase + t][k];
                    r[3 * t]     = fmaf(sp[0][0], s.x, fmaf(sp[0][1], s.y, sp[0][2] * s.z));
                    r[3 * t + 1] = fmaf(sp[1][0], s.x, fmaf(sp[1][1], s.y, sp[1][2] * s.z));
                    r[3 * t + 2] = fmaf(sp[2][0], s.x, fmaf(sp[2][1], s.y, sp[2][2] * s.z));
                }
#pragma unroll
                for (int v = 0; v < 24; ++v) r[v] = wave_sum63(r[v]);
                if (k == 63) {
                    float4* o4 = reinterpret_cast<float4*>(ob + q * 48 + tbase * 3);
#pragma unroll
                    for (int i = 0; i < 6; ++i)
                        o4[i] = make_float4(r[4 * i], r[4 * i + 1],
                                            r[4 * i + 2], r[4 * i + 3]);
                }
            }
        }
        __syncthreads();
    }
}

extern "C" void kernel_launch(void* const* d_in, const int* in_sizes, int n_in,
                              void* d_out, int out_size, void* d_ws, size_t ws_size,
                              hipStream_t stream) {
    const float* x  = (const float*)d_in[0];   // (128, 2048, 3)
    const float* W1 = (const float*)d_in[1];   // (192, 3)
    const float* W2 = (const float*)d_in[2];   // (3, 192)
    float* out = (float*)d_out;                // (128, 2048, 3)

    const size_t need = (size_t)128 * 1024 * 64 * sizeof(uint4);  // 128 MiB
    if (ws_size >= need) {
        j2_dx<<<dim3(1024), dim3(256), 0, stream>>>(x);
        j2_scan4<<<dim3(128, 4), dim3(64), 0, stream>>>(W1, (unsigned*)d_ws);
        j2_out_einsum<<<dim3(128, 128), dim3(64), 0, stream>>>(
            x, W1, W2, (const uint4*)d_ws, out);
    } else {
        j2_pc_kernel<<<dim3(128), dim3(192), 0, stream>>>(x, W1, W2, out);
    }
}